// Round 1
// baseline (432.238 us; speedup 1.0000x reference)
//
#include <hip/hip_runtime.h>

// Swin-3D window attention fwd. B_=256, nW=128, N1=N2=256, C=256, H=8, hd=32.
#define BH_TOTAL 2048
#define SCALE_Q 0.17677669529663687f

typedef unsigned short ushort;
typedef unsigned int uint;
typedef __attribute__((ext_vector_type(8))) short bf16x8;   // 8 bf16 = 4 VGPRs
typedef __attribute__((ext_vector_type(4))) ushort u16x4;
typedef __attribute__((ext_vector_type(4))) float f32x4;

static __device__ __forceinline__ ushort f2bf(float f) {      // RNE
    union { float f; uint u; } v; v.f = f;
    uint r = (v.u + 0x7fffu + ((v.u >> 16) & 1u)) >> 16;
    return (ushort)r;
}
static __device__ __forceinline__ ushort bfru(float f) {      // round-half-up (hot path)
    union { float f; uint u; } v; v.f = f;
    return (ushort)((v.u + 0x8000u) >> 16);
}
static __device__ __forceinline__ float bflo(uint w) {
    union { uint u; float f; } v; v.u = w << 16; return v.f;
}
static __device__ __forceinline__ float bfhi(uint w) {
    union { uint u; float f; } v; v.u = w & 0xffff0000u; return v.f;
}

// ---------------------------------------------------------------------------
// One-shot fp32 -> bf16 conversion of q, kv, Wq, Wkv, Wp.
// Block ranges: [0,8192) q | [8192,16384) kv | [16384,16416) Wq |
//               [16416,16480) Wkv | [16480,16512) Wp.   8 elems/thread.
// ---------------------------------------------------------------------------
__global__ __launch_bounds__(256)
void cvt_all(const float* __restrict__ q, const float* __restrict__ kv,
             const float* __restrict__ Wq, const float* __restrict__ Wkv,
             const float* __restrict__ Wp,
             ushort* __restrict__ qb, ushort* __restrict__ kvb,
             ushort* __restrict__ wqb, ushort* __restrict__ wkvb,
             ushort* __restrict__ wpb)
{
    const int bid = blockIdx.x, tid = threadIdx.x;
    const float* src; ushort* dst; int base;
    if (bid < 8192)       { src = q;   dst = qb;   base = bid; }
    else if (bid < 16384) { src = kv;  dst = kvb;  base = bid - 8192; }
    else if (bid < 16416) { src = Wq;  dst = wqb;  base = bid - 16384; }
    else if (bid < 16480) { src = Wkv; dst = wkvb; base = bid - 16416; }
    else                  { src = Wp;  dst = wpb;  base = bid - 16480; }
    size_t off = ((size_t)base * 256 + tid) * 8;
    float4 a = *(const float4*)&src[off];
    float4 b = *(const float4*)&src[off + 4];
    bf16x8 p = {(short)f2bf(a.x), (short)f2bf(a.y), (short)f2bf(a.z), (short)f2bf(a.w),
                (short)f2bf(b.x), (short)f2bf(b.y), (short)f2bf(b.z), (short)f2bf(b.w)};
    *(bf16x8*)&dst[off] = p;
}

// ---------------------------------------------------------------------------
// maskP[w][qb][col][jt][r] = mask[w][qb*4+r][jt*16+col]   (bf16, MFMA C order,
// r-contiguous so attn can build a f32x4 C operand with one u16x4 load)
// grid: 128*64 blocks = (w, qb)
// ---------------------------------------------------------------------------
__global__ __launch_bounds__(256)
void mask_pre(const float* __restrict__ mask, ushort* __restrict__ maskP)
{
    __shared__ float rows[1024];
    const int w = blockIdx.x >> 6, qb = blockIdx.x & 63;
    const int tid = threadIdx.x;
    const float* src = mask + (size_t)w * 65536 + qb * 1024;
    #pragma unroll
    for (int i = 0; i < 4; ++i) rows[tid + 256 * i] = src[tid + 256 * i];
    __syncthreads();
    const int jt = tid & 15, col = tid >> 4;
    u16x4 p;
    #pragma unroll
    for (int r = 0; r < 4; ++r) p[r] = f2bf(rows[r * 256 + jt * 16 + col]);
    *(u16x4*)&maskP[(size_t)w * 65536 + qb * 1024 + tid * 4] = p;
}

// biasF[h][qb][col][jt][r] = bias_table[rel_index[(qb*4+r)*256 + jt*16+col]*8 + h]
// fp32 (only 2MB).  grid: 8*64 blocks = (h, qb)
__global__ __launch_bounds__(256)
void bias_pre(const float* __restrict__ bias_table, const int* __restrict__ rel_index,
              float* __restrict__ biasF)
{
    __shared__ int idx[1024];
    const int h = blockIdx.x >> 6, qb = blockIdx.x & 63;
    const int tid = threadIdx.x;
    const int* src = rel_index + qb * 1024;
    #pragma unroll
    for (int i = 0; i < 4; ++i) idx[tid + 256 * i] = src[tid + 256 * i];
    __syncthreads();
    const int jt = tid & 15, col = tid >> 4;
    f32x4 p;
    #pragma unroll
    for (int r = 0; r < 4; ++r)
        p[r] = bias_table[idx[r * 256 + jt * 16 + col] * 8 + h];
    *(f32x4*)&biasF[(size_t)h * 65536 + qb * 1024 + tid * 4] = p;
}

// ---------------------------------------------------------------------------
// bf16-MFMA GEMM: C(M x N) = A(M x 256) @ W(N x 256)^T + bias.
// A and W are PRE-CONVERTED bf16 -> staging is pure b128 copies (no VALU cvt).
// 128x128 tile, BK=64, 4 waves each 64x64 (4x4 of 16x16x32 MFMA).
// grid = (n_tiles, 512): n fastest so blocks sharing an A tile are adjacent.
// Epilogues: MODE 0 qh bf16 scaled; MODE 1 k bf16 / vt bf16 transposed;
// MODE 2 fp32 row-major.
// ---------------------------------------------------------------------------
template<int MODE>
__global__ __launch_bounds__(256)
void gemm_mfma(const ushort* __restrict__ A, const ushort* __restrict__ W,
               const float* __restrict__ bias, float* __restrict__ outf,
               ushort* __restrict__ outh0, ushort* __restrict__ outh1)
{
    __shared__ ushort As[128 * 72];   // [m][k], stride 64+8
    __shared__ ushort Bs[128 * 72];   // [n][k]

    const int tid  = threadIdx.x;
    const int n0   = blockIdx.x * 128;
    const int m0   = blockIdx.y * 128;
    const int lane = tid & 63, wave = tid >> 6;
    const int col  = lane & 15, quad = lane >> 4;
    const int wm   = (wave >> 1) * 64, wn = (wave & 1) * 64;

    f32x4 acc[4][4];
    #pragma unroll
    for (int i = 0; i < 4; ++i)
        #pragma unroll
        for (int j = 0; j < 4; ++j)
            acc[i][j] = (f32x4){0.f, 0.f, 0.f, 0.f};

    for (int k0 = 0; k0 < 256; k0 += 64) {
        __syncthreads();
        #pragma unroll
        for (int i = 0; i < 4; ++i) {
            int f = tid + 256 * i;            // 1024 bf16x8 chunks
            int row = f >> 3, c8 = f & 7;
            *(bf16x8*)&As[row * 72 + c8 * 8] =
                *(const bf16x8*)&A[(size_t)(m0 + row) * 256 + k0 + c8 * 8];
        }
        #pragma unroll
        for (int i = 0; i < 4; ++i) {
            int f = tid + 256 * i;
            int row = f >> 3, c8 = f & 7;
            *(bf16x8*)&Bs[row * 72 + c8 * 8] =
                *(const bf16x8*)&W[(size_t)(n0 + row) * 256 + k0 + c8 * 8];
        }
        __syncthreads();
        #pragma unroll
        for (int ks = 0; ks < 64; ks += 32) {
            bf16x8 af[4], bfr[4];
            #pragma unroll
            for (int t = 0; t < 4; ++t) {
                af[t]  = *(const bf16x8*)&As[(wm + t * 16 + col) * 72 + ks + quad * 8];
                bfr[t] = *(const bf16x8*)&Bs[(wn + t * 16 + col) * 72 + ks + quad * 8];
            }
            #pragma unroll
            for (int mt = 0; mt < 4; ++mt)
                #pragma unroll
                for (int nt = 0; nt < 4; ++nt)
                    acc[mt][nt] = __builtin_amdgcn_mfma_f32_16x16x32_bf16(
                        af[mt], bfr[nt], acc[mt][nt], 0, 0, 0);
        }
    }

    // epilogue: m = m0+wm+mt*16+quad*4+r, n = n0+wn+nt*16+col
    #pragma unroll
    for (int mt = 0; mt < 4; ++mt) {
        const int mb = m0 + wm + mt * 16 + quad * 4;
        #pragma unroll
        for (int nt = 0; nt < 4; ++nt) {
            const int n = n0 + wn + nt * 16 + col;
            const float bn = bias[n];
            if (MODE == 1 && n >= 256) {
                // V: 4 row-contiguous vals -> one 8B store, transposed layout
                const int nn = n - 256;
                const int b = mb >> 8, m1 = mb & 255;
                u16x4 p;
                #pragma unroll
                for (int r = 0; r < 4; ++r)
                    p[r] = f2bf(acc[mt][nt][r] + bn);
                *(u16x4*)&outh1[(size_t)((b << 3) | (nn >> 5)) * 8192
                                + (nn & 31) * 256 + m1] = p;
            } else {
                #pragma unroll
                for (int r = 0; r < 4; ++r) {
                    int m = mb + r;
                    int b = m >> 8, m1 = m & 255;
                    float v = acc[mt][nt][r] + bn;
                    if (MODE == 0) {
                        outh0[(size_t)((b << 3) | (n >> 5)) * 8192 + m1 * 32 + (n & 31)]
                            = f2bf(v * SCALE_Q);
                    } else if (MODE == 1) {
                        outh0[(size_t)((b << 3) | (n >> 5)) * 8192 + m1 * 32 + (n & 31)]
                            = f2bf(v);
                    } else {
                        outf[(size_t)m * 256 + n] = v;
                    }
                }
            }
        }
    }
}

// ---------------------------------------------------------------------------
// MFMA attention. mask+bias now enter through the MFMA C operand (no unpack
// loop). Blocks swizzled so the 16 (b2,h) blocks sharing a mask window are
// consecutive -> window stays L3/L2 resident.
// ---------------------------------------------------------------------------
__global__ __launch_bounds__(256)
void attn_mfma(const ushort* __restrict__ qh, const ushort* __restrict__ kb,
               const ushort* __restrict__ vt, const ushort* __restrict__ maskP,
               const float* __restrict__ biasF, ushort* __restrict__ xbuf)
{
    __shared__ ushort Ks[256 * 40];
    __shared__ ushort Vts[32 * 264];
    __shared__ ushort Ps[4][16 * 264];

    // swizzle: g = w*16 + (b2*8 + h); window-sharing blocks adjacent
    const int g  = blockIdx.x;
    const int w  = g >> 4;
    const int b2 = (g >> 3) & 1, h = g & 7;
    const int b  = b2 * 128 + w;
    const int bh = b * 8 + h;

    const int tid  = threadIdx.x;
    const int lane = tid & 63, wave = tid >> 6;
    const int col  = lane & 15;
    const int quad = lane >> 4;

    const ushort* __restrict__ Qg  = qh + (size_t)bh * 8192;
    const ushort* __restrict__ Kg  = kb + (size_t)bh * 8192;
    const ushort* __restrict__ Vg  = vt + (size_t)bh * 8192;
    const ushort* __restrict__ MgP = maskP + (size_t)w * 65536;
    const float*  __restrict__ BgF = biasF + (size_t)h * 65536;

    for (int t = tid; t < 1024; t += 256) {
        int j = t >> 2, p = t & 3;
        *(bf16x8*)&Ks[j * 40 + p * 8] = *(const bf16x8*)&Kg[j * 32 + p * 8];
    }
    for (int t = tid; t < 1024; t += 256) {
        int d = t >> 5, p = t & 31;
        *(bf16x8*)&Vts[d * 264 + p * 8] = *(const bf16x8*)&Vg[d * 256 + p * 8];
    }
    __syncthreads();

    ushort* __restrict__ Pw = &Ps[wave][0];
    const f32x4 zero = {0.f, 0.f, 0.f, 0.f};

    for (int it = 0; it < 4; ++it) {
        const int q0 = (wave * 4 + it) * 16;
        const int qb = (q0 >> 2) + quad;            // 4-row block index

        // mask (bf16, u16x4-per-jt) + bias (fp32) in MFMA C layout
        const ushort* mp  = &MgP[(size_t)(qb * 16 + col) * 64];
        const float*  bp2 = &BgF[(size_t)(qb * 16 + col) * 64];
        uint4 mq[8];
        #pragma unroll
        for (int i = 0; i < 8; ++i) mq[i] = *(const uint4*)&mp[i * 8];

        bf16x8 aq = *(const bf16x8*)&Qg[(q0 + col) * 32 + quad * 8];
        f32x4 acc[16];
        #pragma unroll
        for (int jt = 0; jt < 16; ++jt) {
            f32x4 bv = *(const f32x4*)&bp2[jt * 4];
            uint u0, u1;
            if (jt & 1) { u0 = mq[jt >> 1].z; u1 = mq[jt >> 1].w; }
            else        { u0 = mq[jt >> 1].x; u1 = mq[jt >> 1].y; }
            f32x4 c;
            c[0] = bv[0] + bflo(u0);
            c[1] = bv[1] + bfhi(u0);
            c[2] = bv[2] + bflo(u1);
            c[3] = bv[3] + bfhi(u1);
            bf16x8 bk = *(const bf16x8*)&Ks[(jt * 16 + col) * 40 + quad * 8];
            acc[jt] = __builtin_amdgcn_mfma_f32_16x16x32_bf16(aq, bk, c, 0, 0, 0);
        }

        float mx[4], sm[4], inv[4];
        #pragma unroll
        for (int r = 0; r < 4; ++r) {
            float m = acc[0][r];
            #pragma unroll
            for (int jt = 1; jt < 16; ++jt) m = fmaxf(m, acc[jt][r]);
            #pragma unroll
            for (int off = 1; off < 16; off <<= 1) m = fmaxf(m, __shfl_xor(m, off));
            mx[r] = m;
            sm[r] = 0.f;
        }
        #pragma unroll
        for (int jt = 0; jt < 16; ++jt) {
            #pragma unroll
            for (int r = 0; r < 4; ++r) {
                float e = __expf(acc[jt][r] - mx[r]);
                acc[jt][r] = e;
                sm[r] += e;
            }
        }
        #pragma unroll
        for (int r = 0; r < 4; ++r) {
            float s = sm[r];
            #pragma unroll
            for (int off = 1; off < 16; off <<= 1) s += __shfl_xor(s, off);
            inv[r] = 1.0f / s;
        }

        #pragma unroll
        for (int jt = 0; jt < 16; ++jt) {
            #pragma unroll
            for (int r = 0; r < 4; ++r)
                Pw[(quad * 4 + r) * 264 + jt * 16 + col] = bfru(acc[jt][r]);
        }

        f32x4 x0 = zero, x1 = zero;
        #pragma unroll
        for (int kc = 0; kc < 8; ++kc) {
            bf16x8 ap  = *(const bf16x8*)&Pw[col * 264 + kc * 32 + quad * 8];
            bf16x8 bv0 = *(const bf16x8*)&Vts[col * 264 + kc * 32 + quad * 8];
            bf16x8 bv1 = *(const bf16x8*)&Vts[(col + 16) * 264 + kc * 32 + quad * 8];
            x0 = __builtin_amdgcn_mfma_f32_16x16x32_bf16(ap, bv0, x0, 0, 0, 0);
            x1 = __builtin_amdgcn_mfma_f32_16x16x32_bf16(ap, bv1, x1, 0, 0, 0);
        }

        #pragma unroll
        for (int r = 0; r < 4; ++r) {
            int row = q0 + quad * 4 + r;
            size_t base = (size_t)(b * 256 + row) * 256 + h * 32;
            xbuf[base + col]      = f2bf(x0[r] * inv[r]);
            xbuf[base + 16 + col] = f2bf(x1[r] * inv[r]);
        }
    }
}

// ---------------------------------------------------------------------------
extern "C" void kernel_launch(void* const* d_in, const int* in_sizes, int n_in,
                              void* d_out, int out_size, void* d_ws, size_t ws_size,
                              hipStream_t stream)
{
    const float* q          = (const float*)d_in[0];
    const float* kv         = (const float*)d_in[1];
    const float* mask       = (const float*)d_in[2];
    const float* Wq         = (const float*)d_in[3];
    const float* bq         = (const float*)d_in[4];
    const float* Wkv        = (const float*)d_in[5];
    const float* bkv        = (const float*)d_in[6];
    const float* bias_table = (const float*)d_in[7];
    const float* Wp         = (const float*)d_in[8];
    const float* bp         = (const float*)d_in[9];
    const int*   rel_index  = (const int*)d_in[10];
    float* out = (float*)d_out;

    // ws layout (146.5 MB, with phase aliasing):
    //   0      qhb   32MB
    //  32M     qb16 (phase1) -> kbb (phase2)   32MB
    //  64M     vtb   32MB
    //  96M     kvb16 (phase1) -> xb (phase2)   32MB
    // 128M     maskP bf16 16MB
    // 144M     biasF fp32 2MB
    // 146M     Wq/Wkv/Wp bf16 (128K+256K+128K)
    char* ws = (char*)d_ws;
    ushort* qhb   = (ushort*)(ws);
    ushort* qb16  = (ushort*)(ws + (size_t)33554432);
    ushort* kbb   = (ushort*)(ws + (size_t)33554432);
    ushort* vtb   = (ushort*)(ws + (size_t)67108864);
    ushort* kvb16 = (ushort*)(ws + (size_t)100663296);
    ushort* xb    = (ushort*)(ws + (size_t)100663296);
    ushort* mP    = (ushort*)(ws + (size_t)134217728);
    float*  bF    = (float*) (ws + (size_t)150994944);
    ushort* wqb   = (ushort*)(ws + (size_t)153092096);
    ushort* wkvb  = (ushort*)(ws + (size_t)153223168);
    ushort* wpb   = (ushort*)(ws + (size_t)153485312);

    dim3 blk(256);
    cvt_all<<<dim3(16512), blk, 0, stream>>>(q, kv, Wq, Wkv, Wp,
                                             qb16, kvb16, wqb, wkvb, wpb);
    mask_pre<<<dim3(8192), blk, 0, stream>>>(mask, mP);
    bias_pre<<<dim3(512),  blk, 0, stream>>>(bias_table, rel_index, bF);
    gemm_mfma<0><<<dim3(2, 512), blk, 0, stream>>>(qb16,  wqb,  bq,  nullptr, qhb, nullptr);
    gemm_mfma<1><<<dim3(4, 512), blk, 0, stream>>>(kvb16, wkvb, bkv, nullptr, kbb, vtb);
    attn_mfma<<<dim3(BH_TOTAL), blk, 0, stream>>>(qhb, kbb, vtb, mP, bF, xb);
    gemm_mfma<2><<<dim3(2, 512), blk, 0, stream>>>(xb, wpb, bp, out, nullptr, nullptr);
}